// Round 14
// baseline (497.880 us; speedup 1.0000x reference)
//
#include <hip/hip_runtime.h>
#include <math.h>

#define NN 10000
#define EE 320000
#define GG 64
#define NT 157            // ceil(NN/64)
#define NPAD (NT * 64)    // 10048

#define NB 64             // counting-sort blocks
#define CH (EE / NB)      // 5000 edges per block
#define HSTR 10240        // hist2d row stride

typedef __attribute__((ext_vector_type(8))) short short8;
typedef __attribute__((ext_vector_type(4))) float f32x4;

__device__ __forceinline__ float leaky(float x) { return x >= 0.f ? x : 0.2f * x; }

__device__ __forceinline__ unsigned f2bf(float f) {
  unsigned u = __float_as_uint(f);
  return (u + 0x7fffu + ((u >> 16) & 1u)) >> 16;
}
__device__ __forceinline__ float bflo(unsigned v) { return __uint_as_float(v << 16); }
__device__ __forceinline__ float bfhi(unsigned v) { return __uint_as_float(v & 0xffff0000u); }

// ---------------- flag sync (forward-only producer->consumer) ----------------
__device__ __forceinline__ void spin_flag(int* fl, int target) {
  if (threadIdx.x == 0) {
    while (__hip_atomic_load(fl, __ATOMIC_ACQUIRE, __HIP_MEMORY_SCOPE_AGENT) < target)
      __builtin_amdgcn_s_sleep(16);
  }
  __syncthreads();
}
__device__ __forceinline__ void bump_flag(int* fl) {
  __syncthreads();
  if (threadIdx.x == 0) {
    __threadfence();
    __hip_atomic_fetch_add(fl, 1, __ATOMIC_RELEASE, __HIP_MEMORY_SCOPE_AGENT);
  }
}

// ---------------- counting-sort CSR bodies ----------------
__device__ void histA_body(int blk, const int* __restrict__ ei,
                           int* __restrict__ hist2d,
                           ushort* __restrict__ lrank) {
  __shared__ int lh[NN];
  for (int i = threadIdx.x; i < NN; i += 256) lh[i] = 0;
  __syncthreads();
  const int base = blk * CH;
  for (int i = threadIdx.x; i < CH; i += 256) {
    int d = ei[EE + base + i];
    int r = atomicAdd(&lh[d], 1);
    lrank[base + i] = (ushort)r;
  }
  __syncthreads();
  int* hrow = hist2d + (size_t)blk * HSTR;
  for (int i = threadIdx.x; i < NN; i += 256) hrow[i] = lh[i];
}

__device__ __forceinline__ void s1_body(int sb, const int* __restrict__ hist2d,
                                        int* __restrict__ off2d,
                                        int* __restrict__ total) {
  int t = sb * 256 + threadIdx.x;
  if (t >= NN) return;
  int run = 0;
#pragma unroll 8
  for (int b = 0; b < NB; b++) {
    int v = hist2d[(size_t)b * HSTR + t];
    off2d[(size_t)b * HSTR + t] = run;
    run += v;
  }
  total[t] = run;
}

__device__ void scan_body(const int* __restrict__ total,
                          int* __restrict__ rowstart) {
  __shared__ int part[256];
  const int tid = threadIdx.x;
  const int PER = 40;
  int base = tid * PER;
  int local[PER];
  int s = 0;
#pragma unroll
  for (int i = 0; i < PER; i++) {
    int idx = base + i;
    int v = (idx < NN) ? total[idx] : 0;
    local[i] = s;
    s += v;
  }
  part[tid] = s;
  __syncthreads();
  for (int off = 1; off < 256; off <<= 1) {
    int v = (tid >= off) ? part[tid - off] : 0;
    __syncthreads();
    part[tid] += v;
    __syncthreads();
  }
  int pre = (tid == 0) ? 0 : part[tid - 1];
#pragma unroll
  for (int i = 0; i < PER; i++) {
    int idx = base + i;
    if (idx < NN) rowstart[idx] = pre + local[i];
  }
  if (tid == 255) rowstart[NN] = part[255];
}

__device__ __forceinline__ void fillB_body(int bx, const int* __restrict__ ei,
                                           const int* __restrict__ rowstart,
                                           const int* __restrict__ off2d,
                                           const ushort* __restrict__ lrank,
                                           int* __restrict__ esrc) {
  int e = bx * 256 + threadIdx.x;
  if (e >= EE) return;
  int d = ei[EE + e];
  int s = ei[e];
  int blk = e / CH;
  int pos = rowstart[d] + off2d[(size_t)blk * HSTR + d] + (int)lrank[e];
  esrc[pos] = s;
}

// ---------------- pack / zero / gstart bodies ----------------
#define PX_ITEMS (NN * 256 / 8)   // 320000
#define PW1 (512 * 256)           // 131072
#define PW2 (128 * 512)           // 65536
#define PACK_BLKS ((PX_ITEMS + PW1 + PW2) / 256)  // 2018

__device__ __forceinline__ void pack_body(int pb, const float* __restrict__ x,
                                          const float* __restrict__ W1,
                                          const float* __restrict__ W2,
                                          uint4* __restrict__ xb,
                                          ushort* __restrict__ w1hi,
                                          ushort* __restrict__ w2hi) {
  int idx = pb * 256 + threadIdx.x;
  if (idx < PX_ITEMS) {
    const float4* xf = (const float4*)x;
    float4 a = xf[idx * 2], b = xf[idx * 2 + 1];
    uint4 o;
    o.x = f2bf(a.x) | (f2bf(a.y) << 16);
    o.y = f2bf(a.z) | (f2bf(a.w) << 16);
    o.z = f2bf(b.x) | (f2bf(b.y) << 16);
    o.w = f2bf(b.z) | (f2bf(b.w) << 16);
    xb[idx] = o;
  } else if (idx < PX_ITEMS + PW1) {
    int i = idx - PX_ITEMS;
    int c = i >> 8, k = i & 255;
    w1hi[i] = (ushort)f2bf(W1[(size_t)k * 512 + c]);
  } else if (idx < PX_ITEMS + PW1 + PW2) {
    int i = idx - PX_ITEMS - PW1;
    int c = i >> 9, k = i & 511;
    w2hi[i] = (ushort)f2bf(W2[(size_t)k * 128 + c]);
  }
}

__device__ __forceinline__ void gstart_body(int gb, const int* __restrict__ batch,
                                            int* __restrict__ gstart) {
  int i = gb * 256 + threadIdx.x;
  if (i >= NN) return;
  int b = batch[i];
  int prev = (i == 0) ? -1 : batch[i - 1];
  for (int g = prev + 1; g <= b; g++) gstart[g] = i;
  if (i == NN - 1)
    for (int g = b + 1; g <= GG; g++) gstart[g] = NN;
}

// zero as1/ad1 [NN*4] + as2/ad2 [NN] + flags
#define ZERO_BLKS ((NN * 4 + 255) / 256)  // 157
__device__ __forceinline__ void zero_body(int zb, float* __restrict__ as1,
                                          float* __restrict__ ad1,
                                          float* __restrict__ as2,
                                          float* __restrict__ ad2,
                                          int* __restrict__ fl) {
  int i = zb * 256 + threadIdx.x;
  if (i < NN) { as2[i] = 0.f; ad2[i] = 0.f; }
  if (i < NN * 4) { as1[i] = 0.f; ad1[i] = 0.f; }
  if (zb == 0 && threadIdx.x < 8) fl[threadIdx.x] = 0;
}

// ---------------- MFMA GEMM tile body (hi-only weights) ----------------
__device__ void gemmt_body(int chblk, int nodeblk,
                           const ushort* __restrict__ ab,
                           const ushort* __restrict__ whi,
                           unsigned* __restrict__ op,
                           const float* __restrict__ avs,
                           const float* __restrict__ avd,
                           float* __restrict__ as_out,
                           float* __restrict__ ad_out,
                           int K, int C) {
  const int lane = threadIdx.x & 63;
  const int wave = threadIdx.x >> 6;
  const int l15 = lane & 15;
  const int kg = lane >> 4;
  const int ch0 = chblk * 64 + wave * 16;
  const int node0 = nodeblk * 64;
  const ushort* arow_hi = whi + (size_t)(ch0 + l15) * K + kg * 8;
  const ushort* brow = ab + (size_t)(node0 + l15) * K + kg * 8;
  f32x4 acc[4];
#pragma unroll
  for (int f = 0; f < 4; f++) acc[f] = (f32x4){0.f, 0.f, 0.f, 0.f};
  for (int k0 = 0; k0 < K; k0 += 32) {
    short8 ah = *(const short8*)(arow_hi + k0);
#pragma unroll
    for (int f = 0; f < 4; f++) {
      short8 bv = *(const short8*)(brow + (size_t)f * 16 * K + k0);
      acc[f] = __builtin_amdgcn_mfma_f32_16x16x32_bf16(ah, bv, acc[f], 0, 0, 0);
    }
  }
  const int chw = ch0 + kg * 4;
  const int head = ch0 >> 7;
  const int H = C >> 7;
  const float4 s4 = *(const float4*)(avs + chw);
  const float4 d4 = *(const float4*)(avd + chw);
#pragma unroll
  for (int f = 0; f < 4; f++) {
    int node = node0 + f * 16 + l15;
    unsigned u0 = f2bf(acc[f][0]) | (f2bf(acc[f][1]) << 16);
    unsigned u1 = f2bf(acc[f][2]) | (f2bf(acc[f][3]) << 16);
    *(uint2*)(op + (size_t)node * (C >> 1) + (chw >> 1)) = make_uint2(u0, u1);
    float ss = acc[f][0] * s4.x + acc[f][1] * s4.y + acc[f][2] * s4.z + acc[f][3] * s4.w;
    float sd = acc[f][0] * d4.x + acc[f][1] * d4.y + acc[f][2] * d4.z + acc[f][3] * d4.w;
    ss += __shfl_xor(ss, 16, 64); ss += __shfl_xor(ss, 32, 64);
    sd += __shfl_xor(sd, 16, 64); sd += __shfl_xor(sd, 32, 64);
    if (kg == 0 && node < NN) {
      atomicAdd(&as_out[node * H + head], ss);
      atomicAdd(&ad_out[node * H + head], sd);
    }
  }
}

// ---------------- dispatch 1: histA | pack | gstart | zero ----------------
#define GST_BLKS 40
__global__ __launch_bounds__(256) void fusedA_k(const int* __restrict__ ei,
                                                int* __restrict__ hist2d,
                                                ushort* __restrict__ lrank,
                                                const float* __restrict__ x,
                                                const float* __restrict__ W1,
                                                const float* __restrict__ W2,
                                                uint4* __restrict__ xb,
                                                ushort* __restrict__ w1hi,
                                                ushort* __restrict__ w2hi,
                                                const int* __restrict__ batch,
                                                int* __restrict__ gstart,
                                                float* __restrict__ as1,
                                                float* __restrict__ ad1,
                                                float* __restrict__ as2,
                                                float* __restrict__ ad2,
                                                int* __restrict__ fl) {
  int bx = blockIdx.x;
  if (bx < NB) histA_body(bx, ei, hist2d, lrank);
  else if (bx < NB + PACK_BLKS)
    pack_body(bx - NB, x, W1, W2, xb, w1hi, w2hi);
  else if (bx < NB + PACK_BLKS + GST_BLKS)
    gstart_body(bx - NB - PACK_BLKS, batch, gstart);
  else
    zero_body(bx - NB - PACK_BLKS - GST_BLKS, as1, ad1, as2, ad2, fl);
}

// ---------------- dispatch 2: gemm1 || (s1 -> scan -> fillB) ----------------
#define G1_BLKS 628      // 2 tiles each -> 1256 tiles (8 chblks x 157)
#define FILLG_BLKS 640   // 2 segments each -> 1280 segs >= 1250
__global__ __launch_bounds__(256) void fusedBCD_k(const int* __restrict__ ei,
                                                  const int* __restrict__ hist2d,
                                                  int* __restrict__ off2d,
                                                  int* __restrict__ total,
                                                  int* __restrict__ rowstart,
                                                  const ushort* __restrict__ lrank,
                                                  int* __restrict__ esrc,
                                                  const ushort* __restrict__ xb,
                                                  const ushort* __restrict__ w1hi,
                                                  unsigned* __restrict__ h1p,
                                                  const float* __restrict__ a1s,
                                                  const float* __restrict__ a1d,
                                                  float* __restrict__ as1,
                                                  float* __restrict__ ad1,
                                                  int* __restrict__ fl) {
  int bx = blockIdx.x;
  if (bx < G1_BLKS) {
    int t0 = bx, t1 = bx + G1_BLKS;
    gemmt_body(t0 & 7, t0 >> 3, xb, w1hi, h1p, a1s, a1d, as1, ad1, 256, 512);
    gemmt_body(t1 & 7, t1 >> 3, xb, w1hi, h1p, a1s, a1d, as1, ad1, 256, 512);
  } else if (bx < G1_BLKS + GST_BLKS) {
    s1_body(bx - G1_BLKS, hist2d, off2d, total);
    bump_flag(&fl[0]);
  } else if (bx == G1_BLKS + GST_BLKS) {
    spin_flag(&fl[0], GST_BLKS);
    scan_body(total, rowstart);
    bump_flag(&fl[1]);
  } else {
    spin_flag(&fl[1], 1);
    int fb = bx - (G1_BLKS + GST_BLKS + 1);
    fillB_body(fb, ei, rowstart, off2d, lrank, esrc);
    fillB_body(fb + FILLG_BLKS, ei, rowstart, off2d, lrank, esrc);
  }
}

// ---------------- layer-1 softmax + aggregation: 1 wave per node (unroll4) ----------------
#define AGG1_FMA8(W_, HV_)                          \
  acc0.x = fmaf(W_, bflo(HV_.x), acc0.x);           \
  acc0.y = fmaf(W_, bfhi(HV_.x), acc0.y);           \
  acc0.z = fmaf(W_, bflo(HV_.y), acc0.z);           \
  acc0.w = fmaf(W_, bfhi(HV_.y), acc0.w);           \
  acc1.x = fmaf(W_, bflo(HV_.z), acc1.x);           \
  acc1.y = fmaf(W_, bfhi(HV_.z), acc1.y);           \
  acc1.z = fmaf(W_, bflo(HV_.w), acc1.z);           \
  acc1.w = fmaf(W_, bfhi(HV_.w), acc1.w);

__global__ __launch_bounds__(256) void agg1_k(const int* __restrict__ rowstart,
                                              const int* __restrict__ esrc,
                                              const float* __restrict__ as,
                                              const float* __restrict__ ad,
                                              const ushort* __restrict__ h1p,
                                              const float* __restrict__ b1,
                                              uint4* __restrict__ o1b) {
  const int lane = threadIdx.x & 63;
  const int wid = threadIdx.x >> 6;
  const int n = blockIdx.x * 4 + wid;
  const int beg = rowstart[n];
  const int deg = rowstart[n + 1] - beg;
  const int tot = deg + 1;  // + self loop
  const float4* as4 = (const float4*)as;
  const float4 adv = ((const float4*)ad)[n];
  const int head = lane >> 4;

  __shared__ float wlds_all[4][256];
  float* wlds = wlds_all[wid];

  int s0 = n;
  float4 e0 = make_float4(-1e30f, -1e30f, -1e30f, -1e30f);
  if (lane < tot) {
    if (lane < deg) s0 = esrc[beg + lane];
    float4 av = as4[s0];
    e0.x = leaky(av.x + adv.x); e0.y = leaky(av.y + adv.y);
    e0.z = leaky(av.z + adv.z); e0.w = leaky(av.w + adv.w);
  }
  float4 mx = e0;
  for (int i = lane + 64; i < tot; i += 64) {
    int s = (i < deg) ? esrc[beg + i] : n;
    float4 av = as4[s];
    mx.x = fmaxf(mx.x, leaky(av.x + adv.x));
    mx.y = fmaxf(mx.y, leaky(av.y + adv.y));
    mx.z = fmaxf(mx.z, leaky(av.z + adv.z));
    mx.w = fmaxf(mx.w, leaky(av.w + adv.w));
  }
#pragma unroll
  for (int off = 32; off >= 1; off >>= 1) {
    mx.x = fmaxf(mx.x, __shfl_xor(mx.x, off, 64));
    mx.y = fmaxf(mx.y, __shfl_xor(mx.y, off, 64));
    mx.z = fmaxf(mx.z, __shfl_xor(mx.z, off, 64));
    mx.w = fmaxf(mx.w, __shfl_xor(mx.w, off, 64));
  }
  float4 sm;
  sm.x = __expf(e0.x - mx.x); sm.y = __expf(e0.y - mx.y);
  sm.z = __expf(e0.z - mx.z); sm.w = __expf(e0.w - mx.w);
  for (int i = lane + 64; i < tot; i += 64) {
    int s = (i < deg) ? esrc[beg + i] : n;
    float4 av = as4[s];
    sm.x += __expf(leaky(av.x + adv.x) - mx.x);
    sm.y += __expf(leaky(av.y + adv.y) - mx.y);
    sm.z += __expf(leaky(av.z + adv.z) - mx.z);
    sm.w += __expf(leaky(av.w + adv.w) - mx.w);
  }
#pragma unroll
  for (int off = 32; off >= 1; off >>= 1) {
    sm.x += __shfl_xor(sm.x, off, 64);
    sm.y += __shfl_xor(sm.y, off, 64);
    sm.z += __shfl_xor(sm.z, off, 64);
    sm.w += __shfl_xor(sm.w, off, 64);
  }
  float4 inv;
  inv.x = 1.f / (sm.x + 1e-16f); inv.y = 1.f / (sm.y + 1e-16f);
  inv.z = 1.f / (sm.z + 1e-16f); inv.w = 1.f / (sm.w + 1e-16f);

  float4 acc0 = make_float4(0.f, 0.f, 0.f, 0.f);
  float4 acc1 = make_float4(0.f, 0.f, 0.f, 0.f);
  const char* hb = (const char*)h1p + (size_t)lane * 16;

  for (int base = 0; base < tot; base += 64) {
    int sl;
    float4 wl;
    if (base == 0) {
      sl = s0;
      wl.x = __expf(e0.x - mx.x) * inv.x;
      wl.y = __expf(e0.y - mx.y) * inv.y;
      wl.z = __expf(e0.z - mx.z) * inv.z;
      wl.w = __expf(e0.w - mx.w) * inv.w;
    } else {
      int i = base + lane;
      sl = n;
      wl = make_float4(0.f, 0.f, 0.f, 0.f);
      if (i < tot) {
        if (i < deg) sl = esrc[beg + i];
        float4 av = as4[sl];
        wl.x = __expf(leaky(av.x + adv.x) - mx.x) * inv.x;
        wl.y = __expf(leaky(av.y + adv.y) - mx.y) * inv.y;
        wl.z = __expf(leaky(av.z + adv.z) - mx.z) * inv.z;
        wl.w = __expf(leaky(av.w + adv.w) - mx.w) * inv.w;
      }
    }
    *(float4*)&wlds[lane * 4] = wl;   // intra-wave LDS, no barrier needed
    int m = min(64, tot - base);
    int j = 0;
    for (; j + 4 <= m; j += 4) {
      int sA = __builtin_amdgcn_readlane(sl, j);
      int sB = __builtin_amdgcn_readlane(sl, j + 1);
      int sC = __builtin_amdgcn_readlane(sl, j + 2);
      int sD = __builtin_amdgcn_readlane(sl, j + 3);
      uint4 hA = *(const uint4*)(hb + (size_t)sA * 1024);
      uint4 hB = *(const uint4*)(hb + (size_t)sB * 1024);
      uint4 hC = *(const uint4*)(hb + (size_t)sC * 1024);
      uint4 hD = *(const uint4*)(hb + (size_t)sD * 1024);
      float wA = wlds[j * 4 + head];
      float wB = wlds[(j + 1) * 4 + head];
      float wC = wlds[(j + 2) * 4 + head];
      float wD = wlds[(j + 3) * 4 + head];
      AGG1_FMA8(wA, hA)
      AGG1_FMA8(wB, hB)
      AGG1_FMA8(wC, hC)
      AGG1_FMA8(wD, hD)
    }
    for (; j < m; j++) {
      int sA = __builtin_amdgcn_readlane(sl, j);
      float wA = wlds[j * 4 + head];
      uint4 hA = *(const uint4*)(hb + (size_t)sA * 1024);
      AGG1_FMA8(wA, hA)
    }
  }
  const float4* b4 = (const float4*)b1;
  float4 ba = b4[2 * lane], bb = b4[2 * lane + 1];
  float4 r0, r1;
  r0.x = fmaxf(acc0.x + ba.x, 0.f); r0.y = fmaxf(acc0.y + ba.y, 0.f);
  r0.z = fmaxf(acc0.z + ba.z, 0.f); r0.w = fmaxf(acc0.w + ba.w, 0.f);
  r1.x = fmaxf(acc1.x + bb.x, 0.f); r1.y = fmaxf(acc1.y + bb.y, 0.f);
  r1.z = fmaxf(acc1.z + bb.z, 0.f); r1.w = fmaxf(acc1.w + bb.w, 0.f);
  uint4 o;
  o.x = f2bf(r0.x) | (f2bf(r0.y) << 16);
  o.y = f2bf(r0.z) | (f2bf(r0.w) << 16);
  o.z = f2bf(r1.x) | (f2bf(r1.y) << 16);
  o.w = f2bf(r1.z) | (f2bf(r1.w) << 16);
  o1b[(size_t)n * 64 + lane] = o;
}

// ---------------- agg2 body (group g of 4 nodes) ----------------
__device__ void agg2_body(int g, const int* __restrict__ rowstart,
                          const int* __restrict__ esrc,
                          const float* __restrict__ as,
                          const float* __restrict__ ad,
                          const ushort* __restrict__ h2p,
                          const float* __restrict__ b2,
                          float* __restrict__ out2,
                          float* __restrict__ wlds) {
  const int lane = threadIdx.x & 63;
  const int n = g * 4 + (threadIdx.x >> 6);
  const int beg = rowstart[n];
  const int deg = rowstart[n + 1] - beg;
  const int tot = deg + 1;
  const float adv = ad[n];

  int s0 = n;
  float e0 = -1e30f;
  if (lane < tot) {
    if (lane < deg) s0 = esrc[beg + lane];
    e0 = leaky(as[s0] + adv);
  }
  float mx = e0;
  for (int i = lane + 64; i < tot; i += 64) {
    int s = (i < deg) ? esrc[beg + i] : n;
    mx = fmaxf(mx, leaky(as[s] + adv));
  }
#pragma unroll
  for (int off = 32; off >= 1; off >>= 1) mx = fmaxf(mx, __shfl_xor(mx, off, 64));
  float sm = __expf(e0 - mx);
  for (int i = lane + 64; i < tot; i += 64) {
    int s = (i < deg) ? esrc[beg + i] : n;
    sm += __expf(leaky(as[s] + adv) - mx);
  }
#pragma unroll
  for (int off = 32; off >= 1; off >>= 1) sm += __shfl_xor(sm, off, 64);
  float inv = 1.f / (sm + 1e-16f);

  float2 acc = make_float2(0.f, 0.f);
  const char* hb = (const char*)h2p + (size_t)lane * 4;
  for (int base = 0; base < tot; base += 64) {
    int sl;
    float wl;
    if (base == 0) {
      sl = s0;
      wl = __expf(e0 - mx) * inv;
    } else {
      int i = base + lane;
      sl = n; wl = 0.f;
      if (i < tot) {
        if (i < deg) sl = esrc[beg + i];
        wl = __expf(leaky(as[sl] + adv) - mx) * inv;
      }
    }
    wlds[lane] = wl;
    int m = min(64, tot - base);
    int j = 0;
    for (; j + 4 <= m; j += 4) {
      int sA = __builtin_amdgcn_readlane(sl, j);
      int sB = __builtin_amdgcn_readlane(sl, j + 1);
      int sC = __builtin_amdgcn_readlane(sl, j + 2);
      int sD = __builtin_amdgcn_readlane(sl, j + 3);
      unsigned hA = *(const unsigned*)(hb + (size_t)sA * 256);
      unsigned hB = *(const unsigned*)(hb + (size_t)sB * 256);
      unsigned hC = *(const unsigned*)(hb + (size_t)sC * 256);
      unsigned hD = *(const unsigned*)(hb + (size_t)sD * 256);
      float wA = wlds[j], wB = wlds[j + 1], wC = wlds[j + 2], wD = wlds[j + 3];
      acc.x = fmaf(wA, bflo(hA), acc.x);
      acc.y = fmaf(wA, bfhi(hA), acc.y);
      acc.x = fmaf(wB, bflo(hB), acc.x);
      acc.y = fmaf(wB, bfhi(hB), acc.y);
      acc.x = fmaf(wC, bflo(hC), acc.x);
      acc.y = fmaf(wC, bfhi(hC), acc.y);
      acc.x = fmaf(wD, bflo(hD), acc.x);
      acc.y = fmaf(wD, bfhi(hD), acc.y);
    }
    for (; j < m; j++) {
      int sA = __builtin_amdgcn_readlane(sl, j);
      float wA = wlds[j];
      unsigned hA = *(const unsigned*)(hb + (size_t)sA * 256);
      acc.x = fmaf(wA, bflo(hA), acc.x);
      acc.y = fmaf(wA, bfhi(hA), acc.y);
    }
  }
  float2 bb = ((const float2*)b2)[lane];
  float2 r;
  r.x = fmaxf(acc.x + bb.x, 0.f);
  r.y = fmaxf(acc.y + bb.y, 0.f);
  ((float2*)(out2 + (size_t)n * 128))[lane] = r;
}

// ---------------- poolfc body (256 threads) ----------------
__device__ void poolfc_body(int g, const int* __restrict__ gstart,
                            const float* __restrict__ out2,
                            const float* __restrict__ fcw,
                            const float* __restrict__ fcb,
                            float* __restrict__ out,
                            float* __restrict__ pg2 /* [2][128] */,
                            float* __restrict__ pg /* [128] */) {
  const int tid = threadIdx.x;
  const int c = tid & 127;
  const int half = tid >> 7;
  const int beg = gstart[g], end = gstart[g + 1];
  const int cnt = end - beg;
  float acc = 0.f;
  for (int n = beg + half; n < end; n += 2) acc += out2[(size_t)n * 128 + c];
  pg2[half * 128 + c] = acc;
  __syncthreads();
  if (tid < 128) pg[tid] = (pg2[tid] + pg2[128 + tid]) / (float)(cnt > 0 ? cnt : 1);
  __syncthreads();
  if (tid < 64) {
    float o = fcb[tid];
#pragma unroll 8
    for (int cc = 0; cc < 128; cc++) o = fmaf(pg[cc], fcw[cc * 64 + tid], o);
    out[g * 64 + tid] = o;
  }
}

// ---------------- dispatch 4: gemm2 -> agg2 -> poolfc ----------------
#define G2_BLKS 314
#define A2_BLKS 1280   // 2 groups each -> 2560 >= 2500
__global__ __launch_bounds__(256) void fusedEFG_k(const int* __restrict__ rowstart,
                                                  const int* __restrict__ esrc,
                                                  const ushort* __restrict__ o1b,
                                                  const ushort* __restrict__ w2hi,
                                                  unsigned* __restrict__ h2p,
                                                  const float* __restrict__ a2s,
                                                  const float* __restrict__ a2d,
                                                  float* __restrict__ as2,
                                                  float* __restrict__ ad2,
                                                  const float* __restrict__ b2,
                                                  float* __restrict__ out2,
                                                  const int* __restrict__ gstart,
                                                  const float* __restrict__ fcw,
                                                  const float* __restrict__ fcb,
                                                  float* __restrict__ out,
                                                  int* __restrict__ fl) {
  __shared__ float lds[4][64];   // agg2 wlds / poolfc pg2+pg
  int bx = blockIdx.x;
  if (bx < G2_BLKS) {
    gemmt_body(bx & 1, bx >> 1, o1b, w2hi, h2p, a2s, a2d, as2, ad2, 512, 128);
    bump_flag(&fl[2]);
  } else if (bx < G2_BLKS + A2_BLKS) {
    spin_flag(&fl[2], G2_BLKS);
    int g = bx - G2_BLKS;
    agg2_body(g, rowstart, esrc, as2, ad2, (const ushort*)h2p, b2, out2,
              lds[threadIdx.x >> 6]);
    int g2 = g + A2_BLKS;
    if (g2 < NN / 4)
      agg2_body(g2, rowstart, esrc, as2, ad2, (const ushort*)h2p, b2, out2,
                lds[threadIdx.x >> 6]);
    bump_flag(&fl[3]);
  } else {
    spin_flag(&fl[3], A2_BLKS);
    poolfc_body(bx - G2_BLKS - A2_BLKS, gstart, out2, fcw, fcb, out,
                &lds[0][0], &lds[2][0] + 64);
  }
}

// ---------------- launch ----------------
extern "C" void kernel_launch(void* const* d_in, const int* in_sizes, int n_in,
                              void* d_out, int out_size, void* d_ws, size_t ws_size,
                              hipStream_t stream) {
  const float* x   = (const float*)d_in[0];
  const int*   ei  = (const int*)d_in[1];
  const int*   bat = (const int*)d_in[2];
  const float* W1  = (const float*)d_in[3];
  const float* a1s = (const float*)d_in[4];
  const float* a1d = (const float*)d_in[5];
  const float* b1  = (const float*)d_in[6];
  const float* W2  = (const float*)d_in[7];
  const float* a2s = (const float*)d_in[8];
  const float* a2d = (const float*)d_in[9];
  const float* b2  = (const float*)d_in[10];
  const float* fcw = (const float*)d_in[11];
  const float* fcb = (const float*)d_in[12];
  float* out = (float*)d_out;

  char* ws = (char*)d_ws;
  size_t off = 0;
  auto alloc = [&](size_t bytes) -> void* {
    void* p = ws + off;
    off = (off + bytes + 255) & ~(size_t)255;
    return p;
  };

  int*   hist2d   = (int*)alloc((size_t)NB * HSTR * 4);
  int*   off2d    = (int*)alloc((size_t)NB * HSTR * 4);
  ushort* lrank   = (ushort*)alloc((size_t)EE * 2);
  int*   total    = (int*)alloc((size_t)NN * 4);
  int*   rowstart = (int*)alloc((size_t)(NN + 1) * 4);
  int*   esrc     = (int*)alloc((size_t)EE * 4);
  int*   gstart   = (int*)alloc((size_t)(GG + 1) * 4);
  int*   fl       = (int*)alloc(64);
  ushort* xb      = (ushort*)alloc((size_t)NPAD * 256 * 2);
  ushort* w1hi    = (ushort*)alloc((size_t)512 * 256 * 2);
  ushort* w2hi    = (ushort*)alloc((size_t)128 * 512 * 2);
  ushort* h1p     = (ushort*)alloc((size_t)NPAD * 512 * 2);
  ushort* o1b     = (ushort*)alloc((size_t)NPAD * 512 * 2);
  ushort* h2p     = (ushort*)alloc((size_t)NPAD * 128 * 2);
  float* as1      = (float*)alloc((size_t)NN * 4 * 4);
  float* ad1      = (float*)alloc((size_t)NN * 4 * 4);
  float* as2      = (float*)alloc((size_t)NN * 4);
  float* ad2      = (float*)alloc((size_t)NN * 4);
  float* out2     = (float*)alloc((size_t)NN * 128 * 4);
  (void)ws_size; (void)in_sizes; (void)n_in; (void)out_size;

  fusedA_k<<<NB + PACK_BLKS + GST_BLKS + ZERO_BLKS, 256, 0, stream>>>(
      ei, hist2d, lrank, x, W1, W2, (uint4*)xb, w1hi, w2hi, bat, gstart,
      as1, ad1, as2, ad2, fl);

  fusedBCD_k<<<G1_BLKS + GST_BLKS + 1 + FILLG_BLKS, 256, 0, stream>>>(
      ei, hist2d, off2d, total, rowstart, lrank, esrc, xb, w1hi,
      (unsigned*)h1p, a1s, a1d, as1, ad1, fl);

  agg1_k<<<NN / 4, 256, 0, stream>>>(rowstart, esrc, as1, ad1, h1p, b1, (uint4*)o1b);

  fusedEFG_k<<<G2_BLKS + A2_BLKS + GG, 256, 0, stream>>>(
      rowstart, esrc, o1b, w2hi, (unsigned*)h2p, a2s, a2d, as2, ad2, b2, out2,
      gstart, fcw, fcb, out, fl);
}

// Round 15
// 149.154 us; speedup vs baseline: 3.3380x; 3.3380x over previous
//
#include <hip/hip_runtime.h>
#include <math.h>

#define NN 10000
#define EE 320000
#define GG 64
#define NT 157            // ceil(NN/64)
#define NPAD (NT * 64)    // 10048

#define NB 64             // counting-sort blocks
#define CH (EE / NB)      // 5000 edges per block
#define HSTR 10240        // hist2d row stride

typedef __attribute__((ext_vector_type(8))) short short8;
typedef __attribute__((ext_vector_type(4))) float f32x4;

__device__ __forceinline__ float leaky(float x) { return x >= 0.f ? x : 0.2f * x; }

__device__ __forceinline__ unsigned f2bf(float f) {
  unsigned u = __float_as_uint(f);
  return (u + 0x7fffu + ((u >> 16) & 1u)) >> 16;
}
__device__ __forceinline__ float bflo(unsigned v) { return __uint_as_float(v << 16); }
__device__ __forceinline__ float bfhi(unsigned v) { return __uint_as_float(v & 0xffff0000u); }

// ---------------- counting-sort CSR bodies ----------------
__device__ void histA_body(int blk, const int* __restrict__ ei,
                           int* __restrict__ hist2d,
                           ushort* __restrict__ lrank) {
  __shared__ int lh[NN];
  for (int i = threadIdx.x; i < NN; i += 256) lh[i] = 0;
  __syncthreads();
  const int base = blk * CH;
  for (int i = threadIdx.x; i < CH; i += 256) {
    int d = ei[EE + base + i];
    int r = atomicAdd(&lh[d], 1);
    lrank[base + i] = (ushort)r;
  }
  __syncthreads();
  int* hrow = hist2d + (size_t)blk * HSTR;
  for (int i = threadIdx.x; i < NN; i += 256) hrow[i] = lh[i];
}

__device__ __forceinline__ void s1_body(int sb, const int* __restrict__ hist2d,
                                        int* __restrict__ off2d,
                                        int* __restrict__ total) {
  int t = sb * 256 + threadIdx.x;
  if (t >= NN) return;
  int run = 0;
#pragma unroll 8
  for (int b = 0; b < NB; b++) {
    int v = hist2d[(size_t)b * HSTR + t];
    off2d[(size_t)b * HSTR + t] = run;
    run += v;
  }
  total[t] = run;
}

__device__ void scan_body(const int* __restrict__ total,
                          int* __restrict__ rowstart) {
  __shared__ int part[256];
  const int tid = threadIdx.x;
  const int PER = 40;
  int base = tid * PER;
  int local[PER];
  int s = 0;
#pragma unroll
  for (int i = 0; i < PER; i++) {
    int idx = base + i;
    int v = (idx < NN) ? total[idx] : 0;
    local[i] = s;
    s += v;
  }
  part[tid] = s;
  __syncthreads();
  for (int off = 1; off < 256; off <<= 1) {
    int v = (tid >= off) ? part[tid - off] : 0;
    __syncthreads();
    part[tid] += v;
    __syncthreads();
  }
  int pre = (tid == 0) ? 0 : part[tid - 1];
#pragma unroll
  for (int i = 0; i < PER; i++) {
    int idx = base + i;
    if (idx < NN) rowstart[idx] = pre + local[i];
  }
  if (tid == 255) rowstart[NN] = part[255];
}

__device__ __forceinline__ void fillB_body(int bx, const int* __restrict__ ei,
                                           const int* __restrict__ rowstart,
                                           const int* __restrict__ off2d,
                                           const ushort* __restrict__ lrank,
                                           int* __restrict__ esrc) {
  int e = bx * 256 + threadIdx.x;
  if (e >= EE) return;
  int d = ei[EE + e];
  int s = ei[e];
  int blk = e / CH;
  int pos = rowstart[d] + off2d[(size_t)blk * HSTR + d] + (int)lrank[e];
  esrc[pos] = s;
}

// ---------------- pack / zero / gstart bodies ----------------
#define PX_ITEMS (NN * 256 / 8)   // 320000
#define PW1 (512 * 256)           // 131072
#define PW2 (128 * 512)           // 65536
#define PACK_BLKS ((PX_ITEMS + PW1 + PW2) / 256)  // 2018

__device__ __forceinline__ void pack_body(int pb, const float* __restrict__ x,
                                          const float* __restrict__ W1,
                                          const float* __restrict__ W2,
                                          uint4* __restrict__ xb,
                                          ushort* __restrict__ w1hi,
                                          ushort* __restrict__ w2hi) {
  int idx = pb * 256 + threadIdx.x;
  if (idx < PX_ITEMS) {
    const float4* xf = (const float4*)x;
    float4 a = xf[idx * 2], b = xf[idx * 2 + 1];
    uint4 o;
    o.x = f2bf(a.x) | (f2bf(a.y) << 16);
    o.y = f2bf(a.z) | (f2bf(a.w) << 16);
    o.z = f2bf(b.x) | (f2bf(b.y) << 16);
    o.w = f2bf(b.z) | (f2bf(b.w) << 16);
    xb[idx] = o;
  } else if (idx < PX_ITEMS + PW1) {
    int i = idx - PX_ITEMS;
    int c = i >> 8, k = i & 255;
    w1hi[i] = (ushort)f2bf(W1[(size_t)k * 512 + c]);
  } else if (idx < PX_ITEMS + PW1 + PW2) {
    int i = idx - PX_ITEMS - PW1;
    int c = i >> 9, k = i & 511;
    w2hi[i] = (ushort)f2bf(W2[(size_t)k * 128 + c]);
  }
}

__device__ __forceinline__ void gstart_body(int gb, const int* __restrict__ batch,
                                            int* __restrict__ gstart) {
  int i = gb * 256 + threadIdx.x;
  if (i >= NN) return;
  int b = batch[i];
  int prev = (i == 0) ? -1 : batch[i - 1];
  for (int g = prev + 1; g <= b; g++) gstart[g] = i;
  if (i == NN - 1)
    for (int g = b + 1; g <= GG; g++) gstart[g] = NN;
}

// zero as1/ad1 [NN*4] + as2/ad2 [NN]
#define ZERO_BLKS ((NN * 4 + 255) / 256)  // 157
__device__ __forceinline__ void zero_body(int zb, float* __restrict__ as1,
                                          float* __restrict__ ad1,
                                          float* __restrict__ as2,
                                          float* __restrict__ ad2) {
  int i = zb * 256 + threadIdx.x;
  if (i < NN) { as2[i] = 0.f; ad2[i] = 0.f; }
  if (i < NN * 4) { as1[i] = 0.f; ad1[i] = 0.f; }
}

// ---------------- MFMA GEMM tile body (hi-only weights) ----------------
__device__ void gemmt_body(int chblk, int nodeblk,
                           const ushort* __restrict__ ab,
                           const ushort* __restrict__ whi,
                           unsigned* __restrict__ op,
                           const float* __restrict__ avs,
                           const float* __restrict__ avd,
                           float* __restrict__ as_out,
                           float* __restrict__ ad_out,
                           int K, int C) {
  const int lane = threadIdx.x & 63;
  const int wave = threadIdx.x >> 6;
  const int l15 = lane & 15;
  const int kg = lane >> 4;
  const int ch0 = chblk * 64 + wave * 16;
  const int node0 = nodeblk * 64;
  const ushort* arow_hi = whi + (size_t)(ch0 + l15) * K + kg * 8;
  const ushort* brow = ab + (size_t)(node0 + l15) * K + kg * 8;
  f32x4 acc[4];
#pragma unroll
  for (int f = 0; f < 4; f++) acc[f] = (f32x4){0.f, 0.f, 0.f, 0.f};
  for (int k0 = 0; k0 < K; k0 += 32) {
    short8 ah = *(const short8*)(arow_hi + k0);
#pragma unroll
    for (int f = 0; f < 4; f++) {
      short8 bv = *(const short8*)(brow + (size_t)f * 16 * K + k0);
      acc[f] = __builtin_amdgcn_mfma_f32_16x16x32_bf16(ah, bv, acc[f], 0, 0, 0);
    }
  }
  const int chw = ch0 + kg * 4;
  const int head = ch0 >> 7;
  const int H = C >> 7;
  const float4 s4 = *(const float4*)(avs + chw);
  const float4 d4 = *(const float4*)(avd + chw);
#pragma unroll
  for (int f = 0; f < 4; f++) {
    int node = node0 + f * 16 + l15;
    unsigned u0 = f2bf(acc[f][0]) | (f2bf(acc[f][1]) << 16);
    unsigned u1 = f2bf(acc[f][2]) | (f2bf(acc[f][3]) << 16);
    *(uint2*)(op + (size_t)node * (C >> 1) + (chw >> 1)) = make_uint2(u0, u1);
    float ss = acc[f][0] * s4.x + acc[f][1] * s4.y + acc[f][2] * s4.z + acc[f][3] * s4.w;
    float sd = acc[f][0] * d4.x + acc[f][1] * d4.y + acc[f][2] * d4.z + acc[f][3] * d4.w;
    ss += __shfl_xor(ss, 16, 64); ss += __shfl_xor(ss, 32, 64);
    sd += __shfl_xor(sd, 16, 64); sd += __shfl_xor(sd, 32, 64);
    if (kg == 0 && node < NN) {
      atomicAdd(&as_out[node * H + head], ss);
      atomicAdd(&ad_out[node * H + head], sd);
    }
  }
}

// ---------------- fused dispatches ----------------
#define FILL_BLKS 1250
#define GST_BLKS 40
// A: histA | pack | gstart | zero
__global__ __launch_bounds__(256) void fusedA_k(const int* __restrict__ ei,
                                                int* __restrict__ hist2d,
                                                ushort* __restrict__ lrank,
                                                const float* __restrict__ x,
                                                const float* __restrict__ W1,
                                                const float* __restrict__ W2,
                                                uint4* __restrict__ xb,
                                                ushort* __restrict__ w1hi,
                                                ushort* __restrict__ w2hi,
                                                const int* __restrict__ batch,
                                                int* __restrict__ gstart,
                                                float* __restrict__ as1,
                                                float* __restrict__ ad1,
                                                float* __restrict__ as2,
                                                float* __restrict__ ad2) {
  int bx = blockIdx.x;
  if (bx < NB) histA_body(bx, ei, hist2d, lrank);
  else if (bx < NB + PACK_BLKS)
    pack_body(bx - NB, x, W1, W2, xb, w1hi, w2hi);
  else if (bx < NB + PACK_BLKS + GST_BLKS)
    gstart_body(bx - NB - PACK_BLKS, batch, gstart);
  else
    zero_body(bx - NB - PACK_BLKS - GST_BLKS, as1, ad1, as2, ad2);
}

__global__ __launch_bounds__(256) void fusedB_k(const int* __restrict__ hist2d,
                                                int* __restrict__ off2d,
                                                int* __restrict__ total,
                                                const ushort* __restrict__ xb,
                                                const ushort* __restrict__ w1hi,
                                                unsigned* __restrict__ h1p,
                                                const float* __restrict__ a1s,
                                                const float* __restrict__ a1d,
                                                float* __restrict__ as1,
                                                float* __restrict__ ad1) {
  int bx = blockIdx.x;
  if (bx < GST_BLKS) { s1_body(bx, hist2d, off2d, total); return; }
  int lb = bx - GST_BLKS;
  int ch = lb % 3, nb = lb / 3;
  gemmt_body(ch, nb, xb, w1hi, h1p, a1s, a1d, as1, ad1, 256, 512);
}

__global__ __launch_bounds__(256) void fusedC_k(const int* __restrict__ total,
                                                int* __restrict__ rowstart,
                                                const ushort* __restrict__ xb,
                                                const ushort* __restrict__ w1hi,
                                                unsigned* __restrict__ h1p,
                                                const float* __restrict__ a1s,
                                                const float* __restrict__ a1d,
                                                float* __restrict__ as1,
                                                float* __restrict__ ad1) {
  int bx = blockIdx.x;
  if (bx == 0) { scan_body(total, rowstart); return; }
  int lb = bx - 1;
  int ch = 3 + lb % 3, nb = lb / 3;
  gemmt_body(ch, nb, xb, w1hi, h1p, a1s, a1d, as1, ad1, 256, 512);
}

__global__ __launch_bounds__(256) void fusedD_k(const int* __restrict__ ei,
                                                const int* __restrict__ rowstart,
                                                const int* __restrict__ off2d,
                                                const ushort* __restrict__ lrank,
                                                int* __restrict__ esrc,
                                                const ushort* __restrict__ xb,
                                                const ushort* __restrict__ w1hi,
                                                unsigned* __restrict__ h1p,
                                                const float* __restrict__ a1s,
                                                const float* __restrict__ a1d,
                                                float* __restrict__ as1,
                                                float* __restrict__ ad1) {
  int bx = blockIdx.x;
  if (bx < FILL_BLKS) { fillB_body(bx, ei, rowstart, off2d, lrank, esrc); return; }
  int lb = bx - FILL_BLKS;
  int ch = 6 + (lb & 1), nb = lb >> 1;
  gemmt_body(ch, nb, xb, w1hi, h1p, a1s, a1d, as1, ad1, 256, 512);
}

__global__ __launch_bounds__(256) void gemmt_k(const ushort* __restrict__ ab,
                                               const ushort* __restrict__ whi,
                                               unsigned* __restrict__ op,
                                               const float* __restrict__ avs,
                                               const float* __restrict__ avd,
                                               float* __restrict__ as_out,
                                               float* __restrict__ ad_out,
                                               int K, int C) {
  gemmt_body(blockIdx.x, blockIdx.y, ab, whi, op, avs, avd, as_out, ad_out, K, C);
}

// ---------------- layer-1 softmax + aggregation: 1 wave per node (unroll4) ----------------
#define AGG1_FMA8(W_, HV_)                          \
  acc0.x = fmaf(W_, bflo(HV_.x), acc0.x);           \
  acc0.y = fmaf(W_, bfhi(HV_.x), acc0.y);           \
  acc0.z = fmaf(W_, bflo(HV_.y), acc0.z);           \
  acc0.w = fmaf(W_, bfhi(HV_.y), acc0.w);           \
  acc1.x = fmaf(W_, bflo(HV_.z), acc1.x);           \
  acc1.y = fmaf(W_, bfhi(HV_.z), acc1.y);           \
  acc1.z = fmaf(W_, bflo(HV_.w), acc1.z);           \
  acc1.w = fmaf(W_, bfhi(HV_.w), acc1.w);

__global__ __launch_bounds__(256) void agg1_k(const int* __restrict__ rowstart,
                                              const int* __restrict__ esrc,
                                              const float* __restrict__ as,
                                              const float* __restrict__ ad,
                                              const ushort* __restrict__ h1p,
                                              const float* __restrict__ b1,
                                              uint4* __restrict__ o1b) {
  const int lane = threadIdx.x & 63;
  const int wid = threadIdx.x >> 6;
  const int n = blockIdx.x * 4 + wid;
  const int beg = rowstart[n];
  const int deg = rowstart[n + 1] - beg;
  const int tot = deg + 1;  // + self loop
  const float4* as4 = (const float4*)as;
  const float4 adv = ((const float4*)ad)[n];
  const int head = lane >> 4;

  __shared__ float wlds_all[4][256];
  float* wlds = wlds_all[wid];

  int s0 = n;
  float4 e0 = make_float4(-1e30f, -1e30f, -1e30f, -1e30f);
  if (lane < tot) {
    if (lane < deg) s0 = esrc[beg + lane];
    float4 av = as4[s0];
    e0.x = leaky(av.x + adv.x); e0.y = leaky(av.y + adv.y);
    e0.z = leaky(av.z + adv.z); e0.w = leaky(av.w + adv.w);
  }
  float4 mx = e0;
  for (int i = lane + 64; i < tot; i += 64) {
    int s = (i < deg) ? esrc[beg + i] : n;
    float4 av = as4[s];
    mx.x = fmaxf(mx.x, leaky(av.x + adv.x));
    mx.y = fmaxf(mx.y, leaky(av.y + adv.y));
    mx.z = fmaxf(mx.z, leaky(av.z + adv.z));
    mx.w = fmaxf(mx.w, leaky(av.w + adv.w));
  }
#pragma unroll
  for (int off = 32; off >= 1; off >>= 1) {
    mx.x = fmaxf(mx.x, __shfl_xor(mx.x, off, 64));
    mx.y = fmaxf(mx.y, __shfl_xor(mx.y, off, 64));
    mx.z = fmaxf(mx.z, __shfl_xor(mx.z, off, 64));
    mx.w = fmaxf(mx.w, __shfl_xor(mx.w, off, 64));
  }
  float4 sm;
  sm.x = __expf(e0.x - mx.x); sm.y = __expf(e0.y - mx.y);
  sm.z = __expf(e0.z - mx.z); sm.w = __expf(e0.w - mx.w);
  for (int i = lane + 64; i < tot; i += 64) {
    int s = (i < deg) ? esrc[beg + i] : n;
    float4 av = as4[s];
    sm.x += __expf(leaky(av.x + adv.x) - mx.x);
    sm.y += __expf(leaky(av.y + adv.y) - mx.y);
    sm.z += __expf(leaky(av.z + adv.z) - mx.z);
    sm.w += __expf(leaky(av.w + adv.w) - mx.w);
  }
#pragma unroll
  for (int off = 32; off >= 1; off >>= 1) {
    sm.x += __shfl_xor(sm.x, off, 64);
    sm.y += __shfl_xor(sm.y, off, 64);
    sm.z += __shfl_xor(sm.z, off, 64);
    sm.w += __shfl_xor(sm.w, off, 64);
  }
  float4 inv;
  inv.x = 1.f / (sm.x + 1e-16f); inv.y = 1.f / (sm.y + 1e-16f);
  inv.z = 1.f / (sm.z + 1e-16f); inv.w = 1.f / (sm.w + 1e-16f);

  float4 acc0 = make_float4(0.f, 0.f, 0.f, 0.f);
  float4 acc1 = make_float4(0.f, 0.f, 0.f, 0.f);
  const char* hb = (const char*)h1p + (size_t)lane * 16;

  for (int base = 0; base < tot; base += 64) {
    int sl;
    float4 wl;
    if (base == 0) {
      sl = s0;
      wl.x = __expf(e0.x - mx.x) * inv.x;
      wl.y = __expf(e0.y - mx.y) * inv.y;
      wl.z = __expf(e0.z - mx.z) * inv.z;
      wl.w = __expf(e0.w - mx.w) * inv.w;
    } else {
      int i = base + lane;
      sl = n;
      wl = make_float4(0.f, 0.f, 0.f, 0.f);
      if (i < tot) {
        if (i < deg) sl = esrc[beg + i];
        float4 av = as4[sl];
        wl.x = __expf(leaky(av.x + adv.x) - mx.x) * inv.x;
        wl.y = __expf(leaky(av.y + adv.y) - mx.y) * inv.y;
        wl.z = __expf(leaky(av.z + adv.z) - mx.z) * inv.z;
        wl.w = __expf(leaky(av.w + adv.w) - mx.w) * inv.w;
      }
    }
    *(float4*)&wlds[lane * 4] = wl;   // intra-wave LDS, no barrier needed
    int m = min(64, tot - base);
    int j = 0;
    for (; j + 4 <= m; j += 4) {
      int sA = __builtin_amdgcn_readlane(sl, j);
      int sB = __builtin_amdgcn_readlane(sl, j + 1);
      int sC = __builtin_amdgcn_readlane(sl, j + 2);
      int sD = __builtin_amdgcn_readlane(sl, j + 3);
      uint4 hA = *(const uint4*)(hb + (size_t)sA * 1024);
      uint4 hB = *(const uint4*)(hb + (size_t)sB * 1024);
      uint4 hC = *(const uint4*)(hb + (size_t)sC * 1024);
      uint4 hD = *(const uint4*)(hb + (size_t)sD * 1024);
      float wA = wlds[j * 4 + head];
      float wB = wlds[(j + 1) * 4 + head];
      float wC = wlds[(j + 2) * 4 + head];
      float wD = wlds[(j + 3) * 4 + head];
      AGG1_FMA8(wA, hA)
      AGG1_FMA8(wB, hB)
      AGG1_FMA8(wC, hC)
      AGG1_FMA8(wD, hD)
    }
    for (; j < m; j++) {
      int sA = __builtin_amdgcn_readlane(sl, j);
      float wA = wlds[j * 4 + head];
      uint4 hA = *(const uint4*)(hb + (size_t)sA * 1024);
      AGG1_FMA8(wA, hA)
    }
  }
  const float4* b4 = (const float4*)b1;
  float4 ba = b4[2 * lane], bb = b4[2 * lane + 1];
  float4 r0, r1;
  r0.x = fmaxf(acc0.x + ba.x, 0.f); r0.y = fmaxf(acc0.y + ba.y, 0.f);
  r0.z = fmaxf(acc0.z + ba.z, 0.f); r0.w = fmaxf(acc0.w + ba.w, 0.f);
  r1.x = fmaxf(acc1.x + bb.x, 0.f); r1.y = fmaxf(acc1.y + bb.y, 0.f);
  r1.z = fmaxf(acc1.z + bb.z, 0.f); r1.w = fmaxf(acc1.w + bb.w, 0.f);
  uint4 o;
  o.x = f2bf(r0.x) | (f2bf(r0.y) << 16);
  o.y = f2bf(r0.z) | (f2bf(r0.w) << 16);
  o.z = f2bf(r1.x) | (f2bf(r1.y) << 16);
  o.w = f2bf(r1.z) | (f2bf(r1.w) << 16);
  o1b[(size_t)n * 64 + lane] = o;
}

// ---------------- layer-2 softmax + aggregation: 1 wave per node ----------------
__global__ __launch_bounds__(256) void agg2_k(const int* __restrict__ rowstart,
                                              const int* __restrict__ esrc,
                                              const float* __restrict__ as,
                                              const float* __restrict__ ad,
                                              const ushort* __restrict__ h2p,
                                              const float* __restrict__ b2,
                                              float* __restrict__ out2) {
  const int lane = threadIdx.x & 63;
  const int wid = threadIdx.x >> 6;
  const int n = blockIdx.x * 4 + wid;
  const int beg = rowstart[n];
  const int deg = rowstart[n + 1] - beg;
  const int tot = deg + 1;
  const float adv = ad[n];

  __shared__ float wlds_all[4][64];
  float* wlds = wlds_all[wid];

  int s0 = n;
  float e0 = -1e30f;
  if (lane < tot) {
    if (lane < deg) s0 = esrc[beg + lane];
    e0 = leaky(as[s0] + adv);
  }
  float mx = e0;
  for (int i = lane + 64; i < tot; i += 64) {
    int s = (i < deg) ? esrc[beg + i] : n;
    mx = fmaxf(mx, leaky(as[s] + adv));
  }
#pragma unroll
  for (int off = 32; off >= 1; off >>= 1) mx = fmaxf(mx, __shfl_xor(mx, off, 64));
  float sm = __expf(e0 - mx);
  for (int i = lane + 64; i < tot; i += 64) {
    int s = (i < deg) ? esrc[beg + i] : n;
    sm += __expf(leaky(as[s] + adv) - mx);
  }
#pragma unroll
  for (int off = 32; off >= 1; off >>= 1) sm += __shfl_xor(sm, off, 64);
  float inv = 1.f / (sm + 1e-16f);

  float2 acc = make_float2(0.f, 0.f);
  const char* hb = (const char*)h2p + (size_t)lane * 4;
  for (int base = 0; base < tot; base += 64) {
    int sl;
    float wl;
    if (base == 0) {
      sl = s0;
      wl = __expf(e0 - mx) * inv;
    } else {
      int i = base + lane;
      sl = n; wl = 0.f;
      if (i < tot) {
        if (i < deg) sl = esrc[beg + i];
        wl = __expf(leaky(as[sl] + adv) - mx) * inv;
      }
    }
    wlds[lane] = wl;
    int m = min(64, tot - base);
    int j = 0;
    for (; j + 4 <= m; j += 4) {
      int sA = __builtin_amdgcn_readlane(sl, j);
      int sB = __builtin_amdgcn_readlane(sl, j + 1);
      int sC = __builtin_amdgcn_readlane(sl, j + 2);
      int sD = __builtin_amdgcn_readlane(sl, j + 3);
      unsigned hA = *(const unsigned*)(hb + (size_t)sA * 256);
      unsigned hB = *(const unsigned*)(hb + (size_t)sB * 256);
      unsigned hC = *(const unsigned*)(hb + (size_t)sC * 256);
      unsigned hD = *(const unsigned*)(hb + (size_t)sD * 256);
      float wA = wlds[j], wB = wlds[j + 1], wC = wlds[j + 2], wD = wlds[j + 3];
      acc.x = fmaf(wA, bflo(hA), acc.x);
      acc.y = fmaf(wA, bfhi(hA), acc.y);
      acc.x = fmaf(wB, bflo(hB), acc.x);
      acc.y = fmaf(wB, bfhi(hB), acc.y);
      acc.x = fmaf(wC, bflo(hC), acc.x);
      acc.y = fmaf(wC, bfhi(hC), acc.y);
      acc.x = fmaf(wD, bflo(hD), acc.x);
      acc.y = fmaf(wD, bfhi(hD), acc.y);
    }
    for (; j < m; j++) {
      int sA = __builtin_amdgcn_readlane(sl, j);
      float wA = wlds[j];
      unsigned hA = *(const unsigned*)(hb + (size_t)sA * 256);
      acc.x = fmaf(wA, bflo(hA), acc.x);
      acc.y = fmaf(wA, bfhi(hA), acc.y);
    }
  }
  float2 bb = ((const float2*)b2)[lane];
  float2 r;
  r.x = fmaxf(acc.x + bb.x, 0.f);
  r.y = fmaxf(acc.y + bb.y, 0.f);
  ((float2*)(out2 + (size_t)n * 128))[lane] = r;
}

// ---------------- pooling + FC ----------------
__global__ __launch_bounds__(128) void poolfc_k(const int* __restrict__ gstart,
                                                const float* __restrict__ out2,
                                                const float* __restrict__ fcw,
                                                const float* __restrict__ fcb,
                                                float* __restrict__ out) {
  const int g = blockIdx.x;
  const int tid = threadIdx.x;
  const int beg = gstart[g], end = gstart[g + 1];
  const int cnt = end - beg;
  float acc = 0.f;
  int n = beg;
  for (; n + 4 <= end; n += 4) {
    float v0 = out2[(size_t)(n + 0) * 128 + tid];
    float v1 = out2[(size_t)(n + 1) * 128 + tid];
    float v2 = out2[(size_t)(n + 2) * 128 + tid];
    float v3 = out2[(size_t)(n + 3) * 128 + tid];
    acc += (v0 + v1) + (v2 + v3);
  }
  for (; n < end; n++) acc += out2[(size_t)n * 128 + tid];
  __shared__ float pg[128];
  pg[tid] = acc / (float)(cnt > 0 ? cnt : 1);
  __syncthreads();
  if (tid < 64) {
    float o = fcb[tid];
#pragma unroll 8
    for (int c = 0; c < 128; c++) o = fmaf(pg[c], fcw[c * 64 + tid], o);
    out[g * 64 + tid] = o;
  }
}

// ---------------- launch ----------------
extern "C" void kernel_launch(void* const* d_in, const int* in_sizes, int n_in,
                              void* d_out, int out_size, void* d_ws, size_t ws_size,
                              hipStream_t stream) {
  const float* x   = (const float*)d_in[0];
  const int*   ei  = (const int*)d_in[1];
  const int*   bat = (const int*)d_in[2];
  const float* W1  = (const float*)d_in[3];
  const float* a1s = (const float*)d_in[4];
  const float* a1d = (const float*)d_in[5];
  const float* b1  = (const float*)d_in[6];
  const float* W2  = (const float*)d_in[7];
  const float* a2s = (const float*)d_in[8];
  const float* a2d = (const float*)d_in[9];
  const float* b2  = (const float*)d_in[10];
  const float* fcw = (const float*)d_in[11];
  const float* fcb = (const float*)d_in[12];
  float* out = (float*)d_out;

  char* ws = (char*)d_ws;
  size_t off = 0;
  auto alloc = [&](size_t bytes) -> void* {
    void* p = ws + off;
    off = (off + bytes + 255) & ~(size_t)255;
    return p;
  };

  int*   hist2d   = (int*)alloc((size_t)NB * HSTR * 4);
  int*   off2d    = (int*)alloc((size_t)NB * HSTR * 4);
  ushort* lrank   = (ushort*)alloc((size_t)EE * 2);
  int*   total    = (int*)alloc((size_t)NN * 4);
  int*   rowstart = (int*)alloc((size_t)(NN + 1) * 4);
  int*   esrc     = (int*)alloc((size_t)EE * 4);
  int*   gstart   = (int*)alloc((size_t)(GG + 1) * 4);
  ushort* xb      = (ushort*)alloc((size_t)NPAD * 256 * 2);
  ushort* w1hi    = (ushort*)alloc((size_t)512 * 256 * 2);
  ushort* w2hi    = (ushort*)alloc((size_t)128 * 512 * 2);
  ushort* h1p     = (ushort*)alloc((size_t)NPAD * 512 * 2);
  ushort* o1b     = (ushort*)alloc((size_t)NPAD * 512 * 2);
  ushort* h2p     = (ushort*)alloc((size_t)NPAD * 128 * 2);
  float* as1      = (float*)alloc((size_t)NN * 4 * 4);
  float* ad1      = (float*)alloc((size_t)NN * 4 * 4);
  float* as2      = (float*)alloc((size_t)NN * 4);
  float* ad2      = (float*)alloc((size_t)NN * 4);
  float* out2     = (float*)alloc((size_t)NN * 128 * 4);
  (void)ws_size; (void)in_sizes; (void)n_in; (void)out_size;

  fusedA_k<<<NB + PACK_BLKS + GST_BLKS + ZERO_BLKS, 256, 0, stream>>>(
      ei, hist2d, lrank, x, W1, W2, (uint4*)xb, w1hi, w2hi, bat, gstart,
      as1, ad1, as2, ad2);

  fusedB_k<<<GST_BLKS + 3 * NT, 256, 0, stream>>>(hist2d, off2d, total, xb, w1hi,
                                                  (unsigned*)h1p, a1s, a1d, as1, ad1);

  fusedC_k<<<1 + 3 * NT, 256, 0, stream>>>(total, rowstart, xb, w1hi,
                                           (unsigned*)h1p, a1s, a1d, as1, ad1);

  fusedD_k<<<FILL_BLKS + 2 * NT, 256, 0, stream>>>(ei, rowstart, off2d, lrank, esrc,
                                                   xb, w1hi, (unsigned*)h1p,
                                                   a1s, a1d, as1, ad1);

  agg1_k<<<NN / 4, 256, 0, stream>>>(rowstart, esrc, as1, ad1, h1p, b1, (uint4*)o1b);

  gemmt_k<<<dim3(2, NT), 256, 0, stream>>>(o1b, w2hi, (unsigned*)h2p,
                                           a2s, a2d, as2, ad2, 512, 128);
  agg2_k<<<NN / 4, 256, 0, stream>>>(rowstart, esrc, as2, ad2, h2p, b2, out2);

  poolfc_k<<<GG, 128, 0, stream>>>(gstart, out2, fcw, fcb, out);
}